// Round 6
// baseline (324.054 us; speedup 1.0000x reference)
//
#include <hip/hip_runtime.h>
#include <cstdint>

#define BB 2
#define NN 16384
#define MM 4096
#define CF 256
#define CT 128
#define CP 64

// ================== kernel 0: preprocess refs -> ws float4 ==================
// wsR[j] = (2x, 2y, 2z, rr) — identical math to the proven LDS staging
// (pre-doubling is exact; rr in numpy sum order), done once instead of
// per-block.
__global__ __launch_bounds__(256) void prep_kernel(
    const float* __restrict__ rc,          // [B,M,3] flattened
    float4* __restrict__ wsR)              // [B*M] (+pad)
{
#pragma clang fp contract(off)
    const int j = blockIdx.x * 256 + threadIdx.x;
    if (j < BB * MM) {
        const float x = rc[3 * j + 0];
        const float y = rc[3 * j + 1];
        const float z = rc[3 * j + 2];
        wsR[j] = make_float4(x + x, y + y, z + z, (x * x + y * y) + z * z);
    }
}

// ======================= kernel 1: 3-NN -> workspace =======================
// Round-6 restructure: 1 query PER LANE (64 queries/wave). Every lane needs
// the SAME ref per iteration -> the ref read is wave-uniform (scalar-cache /
// L2 broadcast), eliminating the ds_read_b128 pipe that floored R2 at ~41 us
// (2.1M wave-iters x ~12cyc). No LDS staging, no barriers in the scan, no
// tau/shfl machinery (gate threshold IS the lane's own d2v -- exact: a skip
// can only drop dd==d2v later-index ties, which first-seen semantics drop
// anyway), no butterfly merge. K=2 split: wave h scans refs [h*2048,(h+1)*2048)
// ascending; cross-half merge via LDS lexicographic ins (proven R5 mechanism).
// First 256 refs run the update unconditionally (warmup: while P(take)~1 a
// gate is pure overhead -- R3 lesson). 16-ref register double-buffer pipeline
// hides the uniform-load latency. Bit-exactness: dd formula unchanged
// (pre-doubled refs, numpy order, contract off); strict-< index network;
// min/med3 value network; ascending-j streams.
#define TPB1 128
#define WARM 16      // warmup super-groups (16 refs each -> 256 refs)

__global__ __launch_bounds__(TPB1, 1) void knn_kernel(
    const float* __restrict__ coords,      // [B,N,3]
    const float4* __restrict__ wsR,        // [B*M] preprocessed (+pad)
    int4* __restrict__ wsI,                // [B,N] {i0,i1,i2,-}
    float4* __restrict__ wsW)              // [B,N] {w0,w1,w2,-}
{
#pragma clang fp contract(off)
    __shared__ float mD[64][3];
    __shared__ int   mI[64][3];

    const int tid  = threadIdx.x;
    const int lane = tid & 63;
    const int wu   = __builtin_amdgcn_readfirstlane(tid >> 6);  // wave 0/1
    const int b    = blockIdx.y;
    const int n    = blockIdx.x * 64 + lane;

    const float* cp = coords + ((size_t)b * NN + n) * 3;
    const float cx = cp[0];
    const float cy = cp[1];
    const float cz = cp[2];
    const float cc = (cx * cx + cy * cy) + cz * cz;   // numpy sum order

    float d0 = INFINITY, d1 = INFINITY, d2v = INFINITY;
    int   i0 = 0, i1 = 0, i2 = 0;

    const float4* rp = wsR + (size_t)b * MM + wu * (MM / 2);
    const int jh = wu * (MM / 2);

    // exact top-3 update (proven network)
    auto upd = [&](float dd, int j) {
        const bool l2 = dd < d2v;
        const bool l1 = dd < d1;
        const bool l0 = dd < d0;
        i2 = l2 ? (l1 ? i1 : j) : i2;
        i1 = l1 ? (l0 ? i0 : j) : i1;
        i0 = l0 ? j : i0;
        const float n2  = __builtin_amdgcn_fmed3f(dd, d1, d2v);
        const float n1  = __builtin_amdgcn_fmed3f(dd, d0, d1);
        const float n0v = fminf(dd, d0);
        d2v = n2; d1 = n1; d0 = n0v;
    };

    float4 A[16], B[16];
    #pragma unroll
    for (int k = 0; k < 16; ++k) A[k] = rp[k];      // prime the pipeline

    // one super-group = 16 refs; 128 super-groups = 2048 refs per wave.
    // step: prefetch sg+1 into nxt while processing cur (sg). Last prefetch
    // reads the pad region after wsR (allocated, never processed).
    auto step = [&](float4 (&cur)[16], float4 (&nxt)[16], const int sg) {
        #pragma unroll
        for (int k = 0; k < 16; ++k) nxt[k] = rp[(sg + 1) * 16 + k];
        const int jb = jh + sg * 16;
        if (sg < WARM) {                           // forced-taken warmup
            #pragma unroll
            for (int k = 0; k < 16; ++k) {
                const float4 r = cur[k];
                const float dd = (cc + r.w) - ((cx * r.x + cy * r.y) + cz * r.z);
                upd(dd, jb + k);
            }
        } else {                                   // gated steady state
            #pragma unroll
            for (int kg = 0; kg < 4; ++kg) {
                const float4 ra = cur[kg * 4 + 0];
                const float4 rb = cur[kg * 4 + 1];
                const float4 rc4 = cur[kg * 4 + 2];
                const float4 rd = cur[kg * 4 + 3];
                const float dda = (cc + ra.w) - ((cx * ra.x + cy * ra.y) + cz * ra.z);
                const float ddb = (cc + rb.w) - ((cx * rb.x + cy * rb.y) + cz * rb.z);
                const float ddc = (cc + rc4.w) - ((cx * rc4.x + cy * rc4.y) + cz * rc4.z);
                const float ddd = (cc + rd.w) - ((cx * rd.x + cy * rd.y) + cz * rd.z);
                const float mn = fminf(fminf(dda, ddb), fminf(ddc, ddd));
                if (__any(mn < d2v)) {             // exact: see header
                    if (__any(dda < d2v)) upd(dda, jb + kg * 4 + 0);
                    if (__any(ddb < d2v)) upd(ddb, jb + kg * 4 + 1);
                    if (__any(ddc < d2v)) upd(ddc, jb + kg * 4 + 2);
                    if (__any(ddd < d2v)) upd(ddd, jb + kg * 4 + 3);
                }
            }
        }
    };

    for (int so = 0; so < 64; ++so) {              // 128 super-groups, swapped
        step(A, B, 2 * so);
        step(B, A, 2 * so + 1);
    }

    // -------- cross-half merge (lexicographic: lower index wins ties) -------
    if (wu == 1) {
        mD[lane][0] = d0;  mD[lane][1] = d1;  mD[lane][2] = d2v;
        mI[lane][0] = i0;  mI[lane][1] = i1;  mI[lane][2] = i2;
    }
    __syncthreads();

    if (wu == 0) {
        auto ins = [&](float e, int f) {
            const bool l2 = (e < d2v) || (e == d2v && f < i2);
            const bool l1 = (e < d1)  || (e == d1  && f < i1);
            const bool l0 = (e < d0)  || (e == d0  && f < i0);
            d2v = l2 ? (l1 ? d1 : e) : d2v;  i2 = l2 ? (l1 ? i1 : f) : i2;
            d1  = l1 ? (l0 ? d0 : e) : d1;   i1 = l1 ? (l0 ? i0 : f) : i1;
            d0  = l0 ? e : d0;               i0 = l0 ? f : i0;
        };
        ins(mD[lane][0], mI[lane][0]);
        ins(mD[lane][1], mI[lane][1]);
        ins(mD[lane][2], mI[lane][2]);

        float w0 = 1.0f / (d0  + 1e-8f);     // IEEE divs, numpy order
        float w1 = 1.0f / (d1  + 1e-8f);
        float w2 = 1.0f / (d2v + 1e-8f);
        const float sum = (w0 + w1) + w2;
        wsI[(size_t)b * NN + n] = make_int4(i0, i1, i2, 0);
        wsW[(size_t)b * NN + n] = make_float4(w0 / sum, w1 / sum, w2 / sum, 0.0f);
    }
}

// ===================== kernel 2: row-staged interpolation ====================
// Unchanged (proven ~24 us): 2 rows per block halves idx/w L2 re-reads;
// software-pipelined ws loads hide L2 latency.
#define TPB2 512
#define NIB  (BB * (CF + CT) / 2)   // 384 interp blocks (2 rows each)
#define NCB  32                     // copy blocks (4 pf rows each)

__global__ __launch_bounds__(TPB2, 8) void interp_kernel(
    const float* __restrict__ refF,        // [B,256,M]
    const float* __restrict__ refT,        // [B,128,M]
    const float* __restrict__ pf,          // [B,64,N]
    const int4*  __restrict__ wsI,         // [B,N]
    const float4* __restrict__ wsW,        // [B,N]
    float* __restrict__ out)               // [B,320,N] ++ [B,128,N]
{
#pragma clang fp contract(off)
    __shared__ float rowA[MM];             // 16 KB
    __shared__ float rowB[MM];             // 16 KB
    const int tid  = threadIdx.x;
    const int task = blockIdx.x;
    const size_t outT_base = (size_t)BB * (CF + CP) * NN;

    if (task >= NIB) {                     // -------- pf copy blocks --------
        const int t3 = task - NIB;         // 0..31, 4 rows each
        for (int j = 0; j < 4; ++j) {
            const int r  = t3 * 4 + j;
            const int bb = r >> 6;
            const int c  = r & (CP - 1);
            const float4* s4 = (const float4*)(pf + ((size_t)bb * CP + c) * NN);
            float4* d4 = (float4*)(out + ((size_t)bb * (CF + CP) + CF + c) * NN);
            for (int i = tid; i < NN / 4; i += TPB2) d4[i] = s4[i];
        }
        return;                            // block-uniform exit
    }

    const int r0 = task * 2;               // rows r0, r0+1 (same b, same class)
    const float* src0;
    float* dst0;
    int b;
    if (r0 < BB * CF) {                    // interpolated features
        b = r0 >> 8;
        const int c = r0 & (CF - 1);
        src0 = refF + ((size_t)b * CF + c) * MM;
        dst0 = out + ((size_t)b * (CF + CP) + c) * NN;
    } else {                               // interpolated t_embed
        const int r2 = r0 - BB * CF;
        b = r2 >> 7;
        const int c = r2 & (CT - 1);
        src0 = refT + ((size_t)b * CT + c) * MM;
        dst0 = out + outT_base + ((size_t)b * CT + c) * NN;
    }
    const float* src1 = src0 + MM;
    float* dst1 = dst0 + NN;

    for (int i = tid; i < MM / 4; i += TPB2) {
        ((float4*)rowA)[i] = ((const float4*)src0)[i];
        ((float4*)rowB)[i] = ((const float4*)src1)[i];
    }
    __syncthreads();

    const int4*   wi = wsI + (size_t)b * NN;
    const float4* ww = wsW + (size_t)b * NN;

    auto clampi = [](int v) { return v < 0 ? 0 : (v > MM - 1 ? MM - 1 : v); };

    int4   id = wi[tid];
    float4 w  = ww[tid];
    for (int nq = tid; nq < NN; nq += TPB2) {
        const int nq2 = nq + TPB2;
        int4   idn;
        float4 wn;
        if (nq2 < NN) { idn = wi[nq2]; wn = ww[nq2]; }   // prefetch next
        const int a0 = clampi(id.x), a1 = clampi(id.y), a2 = clampi(id.z);
        dst0[nq] = (w.x * rowA[a0] + w.y * rowA[a1]) + w.z * rowA[a2];
        dst1[nq] = (w.x * rowB[a0] + w.y * rowB[a1]) + w.z * rowB[a2];
        id = idn; w = wn;
    }
}

extern "C" void kernel_launch(void* const* d_in, const int* in_sizes, int n_in,
                              void* d_out, int out_size, void* d_ws, size_t ws_size,
                              hipStream_t stream) {
    const float* coords     = (const float*)d_in[0];
    const float* ref_coords = (const float*)d_in[1];
    const float* refF       = (const float*)d_in[2];
    const float* refT       = (const float*)d_in[3];
    const float* pf         = (const float*)d_in[4];
    float* out = (float*)d_out;

    // ws layout: wsR (8192 + 16 pad float4 = 131,328 B) | wsI | wsW
    const size_t WSR_BYTES = (size_t)(BB * MM + 16) * sizeof(float4);
    float4* wsR = (float4*)d_ws;
    int4*   wsI = (int4*)((char*)d_ws + WSR_BYTES);
    float4* wsW = (float4*)((char*)d_ws + WSR_BYTES + (size_t)BB * NN * sizeof(int4));

    hipLaunchKernelGGL(prep_kernel, dim3((BB * MM + 255) / 256), dim3(256), 0, stream,
                       ref_coords, wsR);
    hipLaunchKernelGGL(knn_kernel, dim3(NN / 64, BB), dim3(TPB1), 0, stream,
                       coords, wsR, wsI, wsW);
    hipLaunchKernelGGL(interp_kernel, dim3(NIB + NCB), dim3(TPB2), 0, stream,
                       refF, refT, pf, wsI, wsW, out);
}

// Round 7
// 160.718 us; speedup vs baseline: 2.0163x; 2.0163x over previous
//
#include <hip/hip_runtime.h>
#include <cstdint>

#define BB 2
#define NN 16384
#define MM 4096
#define CF 256
#define CT 128
#define CP 64

// ======================= kernel 1: 3-NN -> workspace =======================
// EXACT round-2 kernel — the measured-best knn (70.0 us, Occupancy 37%,
// VGPR 16). Rounds 3-6 tried: wider gate coverage (84.5), branchless Q=2
// (92), split-K occupancy 61% (78), uniform-load restructure (218, scratch
// spill) — all regressed. This config is a deep local minimum; do not vary
// it together with anything else.
// Bit-exactness: pre-doubled refs (fl(c*2r)=2fl(cr), fl(2a+2b)=2fl(a+b) at
// N(0,1) scales), numpy sum order, contract off; strict-< index network
// (first-seen tie = lowest j, ascending scan); min/med3 exact value network;
// tau-pruned wave-uniform gate (a skip can only drop dd that cannot enter
// the global top-3); lexicographic butterfly merge (stable top_k tie rule).
#define TPB1 512
#define NPB1 64
#define CHUNK 2048

__global__ __launch_bounds__(TPB1, 4) void knn_kernel(
    const float* __restrict__ coords,      // [B,N,3]
    const float* __restrict__ ref_coords,  // [B,M,3]
    int4* __restrict__ wsI,                // [B,N] {i0,i1,i2,-}
    float4* __restrict__ wsW)              // [B,N] {w0,w1,w2,-}
{
#pragma clang fp contract(off)
    __shared__ float4 refs[CHUNK];      // 32 KB (2x, 2y, 2z, rr)

    const int tid = threadIdx.x;
    const int b   = blockIdx.y;
    const int n0  = blockIdx.x * NPB1;

    const int pl = tid >> 3;            // point-in-block 0..63
    const int s  = tid & 7;             // sub-lane 0..7
    const int n  = n0 + pl;

    const float* cp = coords + ((size_t)b * NN + n) * 3;
    const float cx = cp[0];
    const float cy = cp[1];
    const float cz = cp[2];
    const float cc = (cx * cx + cy * cy) + cz * cz;   // numpy sum order

    float d0 = INFINITY, d1 = INFINITY, d2v = INFINITY;
    int   i0 = 0, i1 = 0, i2 = 0;
    float tau = INFINITY;               // group pruning threshold
    float thr = INFINITY;               // min(d2v, tau), kept in a register

    const float* rc = ref_coords + (size_t)b * MM * 3;

    for (int ch = 0; ch < MM / CHUNK; ++ch) {
        __syncthreads();                 // refs[] reuse guard
        for (int e = tid; e < CHUNK; e += TPB1) {
            const int j = ch * CHUNK + e;
            const float x = rc[3 * j + 0];
            const float y = rc[3 * j + 1];
            const float z = rc[3 * j + 2];
            // rr from ORIGINAL coords (numpy order); xyz pre-doubled (exact)
            refs[e] = make_float4(x + x, y + y, z + z, (x * x + y * y) + z * z);
        }
        __syncthreads();

        const int jbase = ch * CHUNK;
        for (int it0 = 0; it0 < CHUNK / 8; it0 += 32) {
            #pragma unroll 4
            for (int k = 0; k < 32; ++k) {
                const int e = s + ((it0 + k) << 3);
                const float4 r = refs[e];
                // dot2 == 2*((cx*rx + cy*ry) + cz*rz) bit-exactly
                const float dot2 = (cx * r.x + cy * r.y) + cz * r.z;
                const float dd   = (cc + r.w) - dot2;        // == numpy d2
                // Wave-uniform skip: if no lane beats its threshold, every
                // lane's dd is provably dead (>= d2v local no-op, or >= tau
                // globally dominated). Body is the ORIGINAL exact update.
                if (__any(dd < thr)) {
                    const int j = jbase + e;
                    const bool l2 = dd < d2v;
                    const bool l1 = dd < d1;
                    const bool l0 = dd < d0;
                    i2 = l2 ? (l1 ? i1 : j) : i2;
                    i1 = l1 ? (l0 ? i0 : j) : i1;
                    i0 = l0 ? j : i0;
                    const float n2  = __builtin_amdgcn_fmed3f(dd, d1, d2v);
                    const float n1  = __builtin_amdgcn_fmed3f(dd, d0, d1);
                    const float nv0 = fminf(dd, d0);
                    d2v = n2; d1 = n1; d0 = nv0;
                    thr = fminf(d2v, tau);
                }
            }
            // refresh tau = min of the 8 lanes' (same query) d2v
            float t = d2v;
            t = fminf(t, __shfl_xor(t, 1, 64));
            t = fminf(t, __shfl_xor(t, 2, 64));
            t = fminf(t, __shfl_xor(t, 4, 64));
            tau = t;
            thr = fminf(d2v, tau);
        }
    }

    // lexicographic (d, idx) insert: lower index wins exact ties (stable top_k)
    auto ins = [&](float e, int f) {
        const bool l2 = (e < d2v) || (e == d2v && f < i2);
        const bool l1 = (e < d1)  || (e == d1  && f < i1);
        const bool l0 = (e < d0)  || (e == d0  && f < i0);
        d2v = l2 ? (l1 ? d1 : e) : d2v;  i2 = l2 ? (l1 ? i1 : f) : i2;
        d1  = l1 ? (l0 ? d0 : e) : d1;   i1 = l1 ? (l0 ? i0 : f) : i1;
        d0  = l0 ? e : d0;               i0 = l0 ? f : i0;
    };

    // butterfly across the 8 sub-lanes (xor<8 stays in-group, in-wave)
    for (int off = 1; off < 8; off <<= 1) {
        const float e0 = __shfl_xor(d0,  off, 64);
        const float e1 = __shfl_xor(d1,  off, 64);
        const float e2 = __shfl_xor(d2v, off, 64);
        const int   f0 = __shfl_xor(i0,  off, 64);
        const int   f1 = __shfl_xor(i1,  off, 64);
        const int   f2 = __shfl_xor(i2,  off, 64);
        ins(e0, f0);
        ins(e1, f1);
        ins(e2, f2);
    }

    if (s == 0) {
        float w0 = 1.0f / (d0  + 1e-8f);     // IEEE divs, numpy order
        float w1 = 1.0f / (d1  + 1e-8f);
        float w2 = 1.0f / (d2v + 1e-8f);
        const float sum = (w0 + w1) + w2;
        wsI[(size_t)b * NN + n] = make_int4(i0, i1, i2, 0);
        wsW[(size_t)b * NN + n] = make_float4(w0 / sum, w1 / sum, w2 / sum, 0.0f);
    }
}

// ===================== kernel 2: row-staged interpolation ====================
// EXACT round-3 kernel — the measured-best interp (~24 us inferred): 2 rows
// per block halves idx/w L2 re-reads; software-pipelined ws loads hide L2
// latency; pf rows are pure float4 copies. Same fma ordering (contract off)
// -> bit-identical interpolation.
#define TPB2 512
#define NIB  (BB * (CF + CT) / 2)   // 384 interp blocks (2 rows each)
#define NCB  32                     // copy blocks (4 pf rows each)

__global__ __launch_bounds__(TPB2, 8) void interp_kernel(
    const float* __restrict__ refF,        // [B,256,M]
    const float* __restrict__ refT,        // [B,128,M]
    const float* __restrict__ pf,          // [B,64,N]
    const int4*  __restrict__ wsI,         // [B,N]
    const float4* __restrict__ wsW,        // [B,N]
    float* __restrict__ out)               // [B,320,N] ++ [B,128,N]
{
#pragma clang fp contract(off)
    __shared__ float rowA[MM];             // 16 KB
    __shared__ float rowB[MM];             // 16 KB
    const int tid  = threadIdx.x;
    const int task = blockIdx.x;
    const size_t outT_base = (size_t)BB * (CF + CP) * NN;

    if (task >= NIB) {                     // -------- pf copy blocks --------
        const int t3 = task - NIB;         // 0..31, 4 rows each
        for (int j = 0; j < 4; ++j) {
            const int r  = t3 * 4 + j;
            const int bb = r >> 6;
            const int c  = r & (CP - 1);
            const float4* s4 = (const float4*)(pf + ((size_t)bb * CP + c) * NN);
            float4* d4 = (float4*)(out + ((size_t)bb * (CF + CP) + CF + c) * NN);
            for (int i = tid; i < NN / 4; i += TPB2) d4[i] = s4[i];
        }
        return;                            // block-uniform exit
    }

    const int r0 = task * 2;               // rows r0, r0+1 (same b, same class)
    const float* src0;
    float* dst0;
    int b;
    if (r0 < BB * CF) {                    // interpolated features
        b = r0 >> 8;
        const int c = r0 & (CF - 1);
        src0 = refF + ((size_t)b * CF + c) * MM;
        dst0 = out + ((size_t)b * (CF + CP) + c) * NN;
    } else {                               // interpolated t_embed
        const int r2 = r0 - BB * CF;
        b = r2 >> 7;
        const int c = r2 & (CT - 1);
        src0 = refT + ((size_t)b * CT + c) * MM;
        dst0 = out + outT_base + ((size_t)b * CT + c) * NN;
    }
    const float* src1 = src0 + MM;
    float* dst1 = dst0 + NN;

    for (int i = tid; i < MM / 4; i += TPB2) {
        ((float4*)rowA)[i] = ((const float4*)src0)[i];
        ((float4*)rowB)[i] = ((const float4*)src1)[i];
    }
    __syncthreads();

    const int4*   wi = wsI + (size_t)b * NN;
    const float4* ww = wsW + (size_t)b * NN;

    auto clampi = [](int v) { return v < 0 ? 0 : (v > MM - 1 ? MM - 1 : v); };

    int4   id = wi[tid];
    float4 w  = ww[tid];
    for (int nq = tid; nq < NN; nq += TPB2) {
        const int nq2 = nq + TPB2;
        int4   idn;
        float4 wn;
        if (nq2 < NN) { idn = wi[nq2]; wn = ww[nq2]; }   // prefetch next
        const int a0 = clampi(id.x), a1 = clampi(id.y), a2 = clampi(id.z);
        dst0[nq] = (w.x * rowA[a0] + w.y * rowA[a1]) + w.z * rowA[a2];
        dst1[nq] = (w.x * rowB[a0] + w.y * rowB[a1]) + w.z * rowB[a2];
        id = idn; w = wn;
    }
}

extern "C" void kernel_launch(void* const* d_in, const int* in_sizes, int n_in,
                              void* d_out, int out_size, void* d_ws, size_t ws_size,
                              hipStream_t stream) {
    const float* coords     = (const float*)d_in[0];
    const float* ref_coords = (const float*)d_in[1];
    const float* refF       = (const float*)d_in[2];
    const float* refT       = (const float*)d_in[3];
    const float* pf         = (const float*)d_in[4];
    float* out = (float*)d_out;

    int4*   wsI = (int4*)d_ws;
    float4* wsW = (float4*)((char*)d_ws + (size_t)BB * NN * sizeof(int4));

    hipLaunchKernelGGL(knn_kernel, dim3(NN / NPB1, BB), dim3(TPB1), 0, stream,
                       coords, ref_coords, wsI, wsW);
    hipLaunchKernelGGL(interp_kernel, dim3(NIB + NCB), dim3(TPB2), 0, stream,
                       refF, refT, pf, wsI, wsW, out);
}